// Round 10
// baseline (16630.994 us; speedup 1.0000x reference)
//
#include <hip/hip_runtime.h>
#include <cstddef>

#define B_ 128
#define T_ 512
#define I_ 512
#define H_ 1024
#define TH_ (T_ * H_)
#define PSTR3 520             // partial row stride (floats), 16B-aligned
#define LDSN (16 * PSTR3)     // 8320 floats >= 8192 h-stage; 33.3 KB
#define XBN (B_ * H_)         // exchange buffer: 131072 floats = 512 KB each

typedef __attribute__((ext_vector_type(4))) float f32x4;
typedef __attribute__((ext_vector_type(2))) float f32x2;

// 16B system-scope (cross-XCD visible, cache-bypassing) load/store.
__device__ __forceinline__ void ldsys16(f32x4& v, const float* p) {
    asm volatile("global_load_dwordx4 %0, %1, off sc0 sc1"
                 : "=v"(v) : "v"(p) : "memory");
}
__device__ __forceinline__ void stsys16(float* p, f32x4 v) {
    asm volatile("global_store_dwordx4 %0, %1, off sc0 sc1 nt"
                 :: "v"(p), "v"(v) : "memory");
}
__device__ __forceinline__ void waitvm(int n) {
    if (n == 0) asm volatile("s_waitcnt vmcnt(0)" ::: "memory");
    else        asm volatile("s_waitcnt vmcnt(4)" ::: "memory");
    __builtin_amdgcn_sched_barrier(0);
}

// step-t exchange offset: 8 or 12 alternating every 2 steps.
__device__ __forceinline__ float ofs_of(int t) {
    return 8.0f + 4.0f * (float)((t >> 1) & 1);
}

// ---------------------------------------------------------------------------
// Kernel 1: xin = x @ Wi^T + bi -> out rnn_out region [B,T,H]. (unchanged,
// passed rounds 1,2,4,6,7,9)
// ---------------------------------------------------------------------------
__global__ __launch_bounds__(256) void k_input_gemm(
    const float* __restrict__ A, const float* __restrict__ W,
    const float* __restrict__ bi, float* __restrict__ C)
{
    const int nb = blockIdx.x;
    const int mb = blockIdx.y;
    const int tid = threadIdx.x;
    const int tx = tid & 15;
    const int ty = tid >> 4;

    __shared__ float As[16][132];
    __shared__ float Ws[16][132];

    float acc[8][8];
#pragma unroll
    for (int i = 0; i < 8; ++i)
#pragma unroll
        for (int j = 0; j < 8; ++j) acc[i][j] = 0.f;

    const float* Ab = A + (size_t)mb * 128 * I_;
    const float* Wb = W + (size_t)nb * 128 * I_;

    for (int kt = 0; kt < I_; kt += 16) {
        {
            const int r = tid >> 2;
            const int kq = (tid & 3) * 4;
            float4 v0 = *(const float4*)(Ab + (size_t)r * I_ + kt + kq);
            float4 v1 = *(const float4*)(Ab + (size_t)(r + 64) * I_ + kt + kq);
            As[kq + 0][r] = v0.x; As[kq + 1][r] = v0.y;
            As[kq + 2][r] = v0.z; As[kq + 3][r] = v0.w;
            As[kq + 0][r + 64] = v1.x; As[kq + 1][r + 64] = v1.y;
            As[kq + 2][r + 64] = v1.z; As[kq + 3][r + 64] = v1.w;
            float4 w0 = *(const float4*)(Wb + (size_t)r * I_ + kt + kq);
            float4 w1 = *(const float4*)(Wb + (size_t)(r + 64) * I_ + kt + kq);
            Ws[kq + 0][r] = w0.x; Ws[kq + 1][r] = w0.y;
            Ws[kq + 2][r] = w0.z; Ws[kq + 3][r] = w0.w;
            Ws[kq + 0][r + 64] = w1.x; Ws[kq + 1][r + 64] = w1.y;
            Ws[kq + 2][r + 64] = w1.z; Ws[kq + 3][r + 64] = w1.w;
        }
        __syncthreads();

#pragma unroll
        for (int kk = 0; kk < 16; ++kk) {
            float4 a0 = *(const float4*)&As[kk][ty * 8];
            float4 a1 = *(const float4*)&As[kk][ty * 8 + 4];
            float4 b0 = *(const float4*)&Ws[kk][tx * 8];
            float4 b1 = *(const float4*)&Ws[kk][tx * 8 + 4];
            float av[8] = {a0.x, a0.y, a0.z, a0.w, a1.x, a1.y, a1.z, a1.w};
            float bv[8] = {b0.x, b0.y, b0.z, b0.w, b1.x, b1.y, b1.z, b1.w};
#pragma unroll
            for (int i = 0; i < 8; ++i)
#pragma unroll
                for (int j = 0; j < 8; ++j) acc[i][j] += av[i] * bv[j];
        }
        __syncthreads();
    }

    const int n0 = nb * 128 + tx * 8;
    float4 bv0 = *(const float4*)(bi + n0);
    float4 bv1 = *(const float4*)(bi + n0 + 4);
#pragma unroll
    for (int i = 0; i < 8; ++i) {
        const size_t m = (size_t)mb * 128 + ty * 8 + i;
        float4 c0, c1;
        c0.x = acc[i][0] + bv0.x; c0.y = acc[i][1] + bv0.y;
        c0.z = acc[i][2] + bv0.z; c0.w = acc[i][3] + bv0.w;
        c1.x = acc[i][4] + bv1.x; c1.y = acc[i][5] + bv1.y;
        c1.z = acc[i][6] + bv1.z; c1.w = acc[i][7] + bv1.w;
        *(float4*)(C + m * H_ + n0) = c0;
        *(float4*)(C + m * H_ + n0 + 4) = c1;
    }
}

// ---------------------------------------------------------------------------
// Kernel 2: persistent recurrence, value-carrying exchange (round-9-proven
// validation scheme), fattened blocks + 16B asm exchange ops.
// 256 blocks x 256 thr = 1/CU (all-resident by construction: LDS 33.3 KB,
// VGPR capped 512 by launch_bounds(256,1)). Block: bt=bx&15 -> rows m0=8*bt;
// nt=bx>>4 (0..15) -> cols n0=64*nt. Group = 16 blocks sharing bt.
// Thread (c=tid&15, s=tid>>4): cols n0+c*4+j (j=0..3), k = jj*64+s*4+u
// (jj=0..15) -> exact 0..1023 coverage. wreg f32x4[4][16] = 256 VGPR.
// Per step: issue 8x16B sc0sc1 loads -> vmcnt(4) validate k-half0 -> LDS ->
// compute jj0..7 (half1 loads age under compute) -> validate half1 -> LDS ->
// compute jj8..15 -> partial [16][PSTR3] -> reduce(16) -> epilogue (hp from
// OWN prev res in registers) -> pack float4 via shfl, even lanes store
// out (plain) + xbuf (16B sc0sc1 fire-and-forget). 5 syncthreads, no fences,
// no barriers, no deadlock topology.
// ---------------------------------------------------------------------------
__global__ __launch_bounds__(256, 1) void k_rnn(
    const float* __restrict__ Wh, const float* __restrict__ bh,
    const float* __restrict__ h0, float* __restrict__ out,
    float* __restrict__ xbuf)
{
    __shared__ __align__(16) float lds[LDSN]; // union: h[8][1024] / part[16][PSTR3]

    const int bx = blockIdx.x;
    const int bt = bx & 15;
    const int nt = bx >> 4;          // 0..15
    const int m0 = bt * 8;
    const int n0 = nt * 64;
    const int tid = threadIdx.x;
    const int c = tid & 15;          // col group (4 cols)
    const int s = tid >> 4;          // 0..15 k-phase (16-way split)

    // ---- one-time: Wh register-stationary: cols n0+c*4+j, k=jj*64+s*4 ----
    f32x4 wreg[4][16];
#pragma unroll
    for (int j = 0; j < 4; ++j) {
        const float* wp = Wh + (size_t)(n0 + c * 4 + j) * H_ + s * 4;
#pragma unroll
        for (int jj = 0; jj < 16; ++jj)
            wreg[j][jj] = *(const f32x4*)(wp + jj * 64);
    }

    // output cells: thread owns (row r, cols nl, nl+1)
    const int r  = tid >> 5;             // 0..7
    const int nl = 2 * (tid & 31);       // 0..62 even
    const f32x2 bh2 = *(const f32x2*)(bh + n0 + nl);
    f32x2 hp = *(const f32x2*)(h0 + n0 + nl);   // h_{-1} = h0 (batch-tiled)

    for (int t = 0; t < T_; ++t) {
        const size_t g0 = (size_t)(m0 + r) * TH_ + (size_t)t * H_ + n0 + nl;
        const f32x2 xin2 = *(const f32x2*)(out + g0);   // plain cached

        const float* xb = xbuf + (size_t)((t - 1) & 1) * XBN;
        const float osub = ofs_of(t - 1);
        const float olo = osub - 0.5f;
        const float ohi = osub + 1.5f;

        f32x4 v[8];
        if (t == 0) {
            // chunk0 from h0 (row-broadcast), plain
#pragma unroll
            for (int i = 0; i < 4; ++i) {
                const int F = i * 256 + tid;
                const int p = F >> 7, c4 = F & 127;
                const int col = c4 * 4;
                *(f32x4*)&lds[p * 1024 + col] = *(const f32x4*)(h0 + col);
            }
        } else {
            // issue ALL 8 loads (both k-halves)
#pragma unroll
            for (int q = 0; q < 2; ++q)
#pragma unroll
                for (int i = 0; i < 4; ++i) {
                    const int F = i * 256 + tid;
                    const int p = F >> 7, c4 = F & 127;
                    const int col = q * 512 + c4 * 4;
                    ldsys16(v[q * 4 + i], xb + (size_t)(m0 + p) * H_ + col);
                }
            waitvm(4);   // half0 (oldest 4 + anything older) complete
            // validate + retry half0
            for (;;) {
                unsigned bad = 0;
#pragma unroll
                for (int i = 0; i < 4; ++i) {
                    const f32x4 q4 = v[i];
                    const bool ok = (q4.x >= olo) & (q4.x <= ohi) &
                                    (q4.y >= olo) & (q4.y <= ohi) &
                                    (q4.z >= olo) & (q4.z <= ohi) &
                                    (q4.w >= olo) & (q4.w <= ohi);
                    if (!ok) bad |= (1u << i);
                }
                if (!bad) break;
#pragma unroll
                for (int i = 0; i < 4; ++i)
                    if (bad & (1u << i)) {
                        const int F = i * 256 + tid;
                        const int p = F >> 7, c4 = F & 127;
                        ldsys16(v[i], xb + (size_t)(m0 + p) * H_ + c4 * 4);
                    }
                waitvm(0);
            }
#pragma unroll
            for (int i = 0; i < 4; ++i) {
                const int F = i * 256 + tid;
                const int p = F >> 7, c4 = F & 127;
                f32x4 q4 = v[i];
                q4.x -= osub; q4.y -= osub; q4.z -= osub; q4.w -= osub;
                *(f32x4*)&lds[p * 1024 + c4 * 4] = q4;
            }
        }
        __syncthreads();   // (A) half0 staged

        // ---- compute k-half0: jj 0..7 ----
        float acc[8][4];
#pragma unroll
        for (int m = 0; m < 8; ++m)
#pragma unroll
            for (int j = 0; j < 4; ++j) acc[m][j] = 0.f;

#pragma unroll
        for (int m = 0; m < 8; ++m)
#pragma unroll
            for (int jj = 0; jj < 8; ++jj) {
                const f32x4 h4 = *(const f32x4*)&lds[m * 1024 + jj * 64 + s * 4];
#pragma unroll
                for (int j = 0; j < 4; ++j) {
                    acc[m][j] += h4.x * wreg[j][jj].x;
                    acc[m][j] += h4.y * wreg[j][jj].y;
                    acc[m][j] += h4.z * wreg[j][jj].z;
                    acc[m][j] += h4.w * wreg[j][jj].w;
                }
            }

        // ---- stage k-half1 (loads aged under compute) ----
        if (t == 0) {
#pragma unroll
            for (int i = 0; i < 4; ++i) {
                const int F = i * 256 + tid;
                const int p = F >> 7, c4 = F & 127;
                const int col = 512 + c4 * 4;
                *(f32x4*)&lds[p * 1024 + col] = *(const f32x4*)(h0 + col);
            }
        } else {
            waitvm(0);
            for (;;) {
                unsigned bad = 0;
#pragma unroll
                for (int i = 4; i < 8; ++i) {
                    const f32x4 q4 = v[i];
                    const bool ok = (q4.x >= olo) & (q4.x <= ohi) &
                                    (q4.y >= olo) & (q4.y <= ohi) &
                                    (q4.z >= olo) & (q4.z <= ohi) &
                                    (q4.w >= olo) & (q4.w <= ohi);
                    if (!ok) bad |= (1u << i);
                }
                if (!bad) break;
#pragma unroll
                for (int i = 4; i < 8; ++i)
                    if (bad & (1u << i)) {
                        const int F = (i - 4) * 256 + tid;
                        const int p = F >> 7, c4 = F & 127;
                        ldsys16(v[i], xb + (size_t)(m0 + p) * H_ + 512 + c4 * 4);
                    }
                waitvm(0);
            }
#pragma unroll
            for (int i = 4; i < 8; ++i) {
                const int F = (i - 4) * 256 + tid;
                const int p = F >> 7, c4 = F & 127;
                f32x4 q4 = v[i];
                q4.x -= osub; q4.y -= osub; q4.z -= osub; q4.w -= osub;
                *(f32x4*)&lds[p * 1024 + 512 + c4 * 4] = q4;
            }
        }
        __syncthreads();   // (B) half1 staged

        // ---- compute k-half1: jj 8..15 ----
#pragma unroll
        for (int m = 0; m < 8; ++m)
#pragma unroll
            for (int jj = 8; jj < 16; ++jj) {
                const f32x4 h4 = *(const f32x4*)&lds[m * 1024 + jj * 64 + s * 4];
#pragma unroll
                for (int j = 0; j < 4; ++j) {
                    acc[m][j] += h4.x * wreg[j][jj].x;
                    acc[m][j] += h4.y * wreg[j][jj].y;
                    acc[m][j] += h4.z * wreg[j][jj].z;
                    acc[m][j] += h4.w * wreg[j][jj].w;
                }
            }
        __syncthreads();   // (C) h reads done; LDS becomes partial buffer

        // ---- partial write: part[s][m*64 + c*4 .. +3] ----
#pragma unroll
        for (int m = 0; m < 8; ++m) {
            f32x4 pv;
            pv.x = acc[m][0]; pv.y = acc[m][1];
            pv.z = acc[m][2]; pv.w = acc[m][3];
            *(f32x4*)&lds[PSTR3 * s + m * 64 + c * 4] = pv;
        }
        __syncthreads();   // (D)

        // ---- reduce over 16 k-phases: thread owns cells 2*tid, 2*tid+1 ----
        f32x2 red; red.x = 0.f; red.y = 0.f;
#pragma unroll
        for (int g = 0; g < 16; ++g) {
            const f32x2 p2 = *(const f32x2*)&lds[PSTR3 * g + 2 * tid];
            red.x += p2.x; red.y += p2.y;
        }

        // ---- epilogue: pre = h + xin + Wh.h + bh; clamp [0,1] ----
        f32x2 res;
        res.x = fminf(fmaxf(hp.x + xin2.x + red.x + bh2.x, 0.f), 1.f);
        res.y = fminf(fmaxf(hp.y + xin2.y + red.y + bh2.y, 0.f), 1.f);
        hp = res;   // own h_{t}[r][nl..nl+1] for next step

        // pack pairs -> float4, even lanes store
        const unsigned long long mine =
            __builtin_bit_cast(unsigned long long, res);
        const unsigned long long part = __shfl_xor(mine, 1, 64);
        if (!(tid & 1)) {
            const f32x2 pf = __builtin_bit_cast(f32x2, part);
            f32x4 quad;
            quad.x = res.x; quad.y = res.y; quad.z = pf.x; quad.w = pf.y;
            *(f32x4*)(out + g0) = quad;              // plain cached
            if (t == T_ - 1) {
                *(f32x4*)(out + (size_t)B_ * TH_ +
                          (size_t)(m0 + r) * H_ + n0 + nl) = quad;
            } else {
                const float oadd = ofs_of(t);
                f32x4 qo;
                qo.x = quad.x + oadd; qo.y = quad.y + oadd;
                qo.z = quad.z + oadd; qo.w = quad.w + oadd;
                stsys16(xbuf + (size_t)(t & 1) * XBN +
                        (size_t)(m0 + r) * H_ + n0 + nl, qo);
            }
        }
        __syncthreads();   // (E) reduce reads done before next-iter LDS writes
    }
}

extern "C" void kernel_launch(void* const* d_in, const int* in_sizes, int n_in,
                              void* d_out, int out_size, void* d_ws, size_t ws_size,
                              hipStream_t stream)
{
    const float* x  = (const float*)d_in[0];
    const float* Wi = (const float*)d_in[1];
    const float* bi = (const float*)d_in[2];
    const float* Wh = (const float*)d_in[3];
    const float* bh = (const float*)d_in[4];
    const float* h0 = (const float*)d_in[5];
    float* out = (float*)d_out;
    float* xbuf = (float*)d_ws;

    // zero both exchange buffers (kills cross-replay staleness; 0 fails
    // every validation window)
    const size_t need = (size_t)2 * XBN * sizeof(float);
    const size_t zn = ws_size < need ? ws_size : need;
    hipMemsetAsync(d_ws, 0, zn, stream);

    // 1) xin = x @ Wi^T + bi -> out rnn_out region
    k_input_gemm<<<dim3(8, 512), 256, 0, stream>>>(x, Wi, bi, out);

    // 2) persistent recurrence: 256 blocks, 1/CU, all-resident
    k_rnn<<<dim3(256), dim3(256), 0, stream>>>(Wh, bh, h0, out, xbuf);
}

// Round 11
// 5434.210 us; speedup vs baseline: 3.0604x; 3.0604x over previous
//
#include <hip/hip_runtime.h>
#include <cstddef>

#define B_ 128
#define T_ 512
#define I_ 512
#define H_ 1024
#define TH_ (T_ * H_)
#define PSTR 257              // partial-buffer row stride (floats)
#define LDSN (32 * PSTR)      // 8224 floats = 32.9 KB

typedef __attribute__((ext_vector_type(4))) float f32x4;

// 16B system-scope load (bypass L1/L2, read L3 fresh). NO nt: stays in L3.
__device__ __forceinline__ void ldsys16(f32x4& v, const float* p) {
    asm volatile("global_load_dwordx4 %0, %1, off sc0 sc1"
                 : "=v"(v) : "v"(p) : "memory");
}

// ---------------------------------------------------------------------------
// Kernel 1: xin = x @ Wi^T + bi -> out rnn_out region [B,T,H]. (unchanged,
// passed rounds 1,2,4,6,7,9,10)
// ---------------------------------------------------------------------------
__global__ __launch_bounds__(256) void k_input_gemm(
    const float* __restrict__ A, const float* __restrict__ W,
    const float* __restrict__ bi, float* __restrict__ C)
{
    const int nb = blockIdx.x;
    const int mb = blockIdx.y;
    const int tid = threadIdx.x;
    const int tx = tid & 15;
    const int ty = tid >> 4;

    __shared__ float As[16][132];
    __shared__ float Ws[16][132];

    float acc[8][8];
#pragma unroll
    for (int i = 0; i < 8; ++i)
#pragma unroll
        for (int j = 0; j < 8; ++j) acc[i][j] = 0.f;

    const float* Ab = A + (size_t)mb * 128 * I_;
    const float* Wb = W + (size_t)nb * 128 * I_;

    for (int kt = 0; kt < I_; kt += 16) {
        {
            const int r = tid >> 2;
            const int kq = (tid & 3) * 4;
            float4 v0 = *(const float4*)(Ab + (size_t)r * I_ + kt + kq);
            float4 v1 = *(const float4*)(Ab + (size_t)(r + 64) * I_ + kt + kq);
            As[kq + 0][r] = v0.x; As[kq + 1][r] = v0.y;
            As[kq + 2][r] = v0.z; As[kq + 3][r] = v0.w;
            As[kq + 0][r + 64] = v1.x; As[kq + 1][r + 64] = v1.y;
            As[kq + 2][r + 64] = v1.z; As[kq + 3][r + 64] = v1.w;
            float4 w0 = *(const float4*)(Wb + (size_t)r * I_ + kt + kq);
            float4 w1 = *(const float4*)(Wb + (size_t)(r + 64) * I_ + kt + kq);
            Ws[kq + 0][r] = w0.x; Ws[kq + 1][r] = w0.y;
            Ws[kq + 2][r] = w0.z; Ws[kq + 3][r] = w0.w;
            Ws[kq + 0][r + 64] = w1.x; Ws[kq + 1][r + 64] = w1.y;
            Ws[kq + 2][r + 64] = w1.z; Ws[kq + 3][r + 64] = w1.w;
        }
        __syncthreads();

#pragma unroll
        for (int kk = 0; kk < 16; ++kk) {
            float4 a0 = *(const float4*)&As[kk][ty * 8];
            float4 a1 = *(const float4*)&As[kk][ty * 8 + 4];
            float4 b0 = *(const float4*)&Ws[kk][tx * 8];
            float4 b1 = *(const float4*)&Ws[kk][tx * 8 + 4];
            float av[8] = {a0.x, a0.y, a0.z, a0.w, a1.x, a1.y, a1.z, a1.w};
            float bv[8] = {b0.x, b0.y, b0.z, b0.w, b1.x, b1.y, b1.z, b1.w};
#pragma unroll
            for (int i = 0; i < 8; ++i)
#pragma unroll
                for (int j = 0; j < 8; ++j) acc[i][j] += av[i] * bv[j];
        }
        __syncthreads();
    }

    const int n0 = nb * 128 + tx * 8;
    float4 bv0 = *(const float4*)(bi + n0);
    float4 bv1 = *(const float4*)(bi + n0 + 4);
#pragma unroll
    for (int i = 0; i < 8; ++i) {
        const size_t m = (size_t)mb * 128 + ty * 8 + i;
        float4 c0, c1;
        c0.x = acc[i][0] + bv0.x; c0.y = acc[i][1] + bv0.y;
        c0.z = acc[i][2] + bv0.z; c0.w = acc[i][3] + bv0.w;
        c1.x = acc[i][4] + bv1.x; c1.y = acc[i][5] + bv1.y;
        c1.z = acc[i][6] + bv1.z; c1.w = acc[i][7] + bv1.w;
        *(float4*)(C + m * H_ + n0) = c0;
        *(float4*)(C + m * H_ + n0 + 4) = c1;
    }
}

// ---------------------------------------------------------------------------
// Kernel 2: persistent recurrence — round-7 structure with two changes:
// (1) co-resident blocks belong to DIFFERENT row-groups: v=bx>>8, u=bx&255,
//     bt=(u+v)&15, nt=(u>>4)|(v<<4)  -> the 2 blocks/CU stall independently,
//     hiding sync latency under the other chain's compute.
// (2) 16B asm stage loads (sc0 sc1, no nt) -> half the exchange requests.
// Otherwise identical: 512 blocks x 256 thr (2/CU); rows m0=8*bt, cols
// n0=32*nt; thread (c=tid&7, s=tid>>3) -> cols n0+c*4+j, k=jj*128+s*4+u;
// wreg[4][8] f32x4; fence-free flag barrier (32 slots/group).
// ---------------------------------------------------------------------------
__global__ __launch_bounds__(256, 2) void k_rnn(
    const float* __restrict__ Wh, const float* __restrict__ bh,
    const float* __restrict__ h0, float* __restrict__ out,
    unsigned* __restrict__ bar)
{
    __shared__ __align__(16) float lds[LDSN]; // union: h[8][1024] / part[32][PSTR]

    const int bx = blockIdx.x;
    const int u  = bx & 255;
    const int v  = bx >> 8;
    const int bt = (u + v) & 15;
    const int nt = (u >> 4) | (v << 4);   // 0..31 unique within group
    const int m0 = bt * 8;
    const int n0 = nt * 32;
    const int tid = threadIdx.x;
    const int c = tid & 7;          // col group (4 cols)
    const int s = tid >> 3;         // 0..31 k-phase (32-way split)

    // ---- one-time: Wh register-stationary: cols n0+c*4+j, k=jj*128+s*4 ----
    float4 wreg[4][8];
#pragma unroll
    for (int j = 0; j < 4; ++j) {
        const float* wp = Wh + (size_t)(n0 + c * 4 + j) * H_ + s * 4;
#pragma unroll
        for (int jj = 0; jj < 8; ++jj)
            wreg[j][jj] = *(const float4*)(wp + jj * 128);
    }

    const int r  = tid >> 5;         // output row 0..7
    const int nl = tid & 31;         // output col-local
    const float bh1 = bh[n0 + nl];
    unsigned* grp = bar + bt * 32;   // 32 flag slots for this row-group

    for (int t = 0; t < T_; ++t) {
        // ---- stage h_{t-1} rows m0..m0+7 via 16B system-scope loads ----
        const float* hb; size_t rstr;
        if (t == 0) { hb = h0; rstr = 0; }
        else        { hb = out + (size_t)(t - 1) * H_; rstr = TH_; }

        f32x4 stg[8];
#pragma unroll
        for (int i = 0; i < 8; ++i) {
            const int F = i * 256 + tid;   // float4 index 0..2047
            const int p = F >> 8;          // row 0..7 (256 float4/row)
            const int c4 = F & 255;
            ldsys16(stg[i], hb + (size_t)(m0 + p) * rstr + (size_t)c4 * 4);
        }
        // xin prefetch (own cell; plain cached load)
        const size_t g0 = (size_t)(m0 + r) * TH_ + (size_t)t * H_ + n0 + nl;
        const float xin1 = out[g0];

        asm volatile("s_waitcnt vmcnt(0)" ::: "memory");
        __builtin_amdgcn_sched_barrier(0);
#pragma unroll
        for (int i = 0; i < 8; ++i) {
            const int F = i * 256 + tid;
            const int p = F >> 8;
            const int c4 = F & 255;
            *(f32x4*)&lds[p * 1024 + c4 * 4] = stg[i];
        }
        __syncthreads();

        // h_prev for epilogue (read before LDS reuse)
        const float hp1 = lds[r * 1024 + n0 + nl];

        // ---- compute: acc[m][j] over this thread's 32-k slice ----
        float acc[8][4];
#pragma unroll
        for (int m = 0; m < 8; ++m)
#pragma unroll
            for (int j = 0; j < 4; ++j) acc[m][j] = 0.f;

#pragma unroll
        for (int m = 0; m < 8; ++m) {
#pragma unroll
            for (int jj = 0; jj < 8; ++jj) {
                float4 h4 = *(const float4*)&lds[m * 1024 + jj * 128 + s * 4];
#pragma unroll
                for (int j = 0; j < 4; ++j) {
                    acc[m][j] += h4.x * wreg[j][jj].x;
                    acc[m][j] += h4.y * wreg[j][jj].y;
                    acc[m][j] += h4.z * wreg[j][jj].z;
                    acc[m][j] += h4.w * wreg[j][jj].w;
                }
            }
        }
        __syncthreads();   // h reads done; LDS becomes partial buffer

        // ---- partial write: part[s][m*32 + c*4 + j] ----
#pragma unroll
        for (int m = 0; m < 8; ++m)
#pragma unroll
            for (int j = 0; j < 4; ++j)
                lds[PSTR * s + m * 32 + c * 4 + j] = acc[m][j];
        __syncthreads();

        // ---- reduce over 32 k-phases: thread owns flat cell tid ----
        float red = 0.f;
#pragma unroll
        for (int g = 0; g < 32; ++g)
            red += lds[PSTR * g + tid];

        // ---- epilogue: pre = h + xin + Wh.h + bh; clamp [0,1] ----
        const float res = fminf(fmaxf(hp1 + xin1 + red + bh1, 0.f), 1.f);
        // h store: system-scope write-through so group peers read fresh L3
        __hip_atomic_store(out + g0, res, __ATOMIC_RELAXED,
                           __HIP_MEMORY_SCOPE_SYSTEM);
        if (t == T_ - 1) {
            out[(size_t)B_ * TH_ + (size_t)(m0 + r) * H_ + n0 + nl] = res;
        }

        // ---- fence-free group barrier: release = vmcnt(0) + flag store ----
        asm volatile("s_waitcnt vmcnt(0)" ::: "memory");  // own stores acked
        __syncthreads();                                   // whole block done
        if (tid == 0) {
            __hip_atomic_store(&grp[nt], (unsigned)(t + 1), __ATOMIC_RELAXED,
                               __HIP_MEMORY_SCOPE_SYSTEM);
        }
        if (tid < 64) {
            const unsigned tgt = (unsigned)(t + 1);
            for (;;) {
                unsigned vfl = __hip_atomic_load(&grp[tid & 31], __ATOMIC_RELAXED,
                                                 __HIP_MEMORY_SCOPE_SYSTEM);
                if (__all(vfl >= tgt)) break;
                __builtin_amdgcn_s_sleep(1);
            }
        }
        __syncthreads();
    }
}

extern "C" void kernel_launch(void* const* d_in, const int* in_sizes, int n_in,
                              void* d_out, int out_size, void* d_ws, size_t ws_size,
                              hipStream_t stream)
{
    const float* x  = (const float*)d_in[0];
    const float* Wi = (const float*)d_in[1];
    const float* bi = (const float*)d_in[2];
    const float* Wh = (const float*)d_in[3];
    const float* bh = (const float*)d_in[4];
    const float* h0 = (const float*)d_in[5];
    float* out = (float*)d_out;
    unsigned* bar = (unsigned*)d_ws;

    // zero flag slots (16 groups * 32 slots * 4 B = 2048 B)
    const size_t zn = ws_size < 2048 ? ws_size : 2048;
    hipMemsetAsync(d_ws, 0, zn, stream);

    // 1) xin = x @ Wi^T + bi -> out rnn_out region
    k_input_gemm<<<dim3(8, 512), 256, 0, stream>>>(x, Wi, bi, out);

    // 2) persistent recurrence: 512 blocks, 2/CU, co-residents in
    //    different sync groups (phase overlap)
    k_rnn<<<dim3(512), dim3(256), 0, stream>>>(Wh, bh, h0, out, bar);
}